// Round 8
// baseline (338.510 us; speedup 1.0000x reference)
//
#include <hip/hip_runtime.h>
#include <math.h>

#define ED      256       // EMBED_DIM
#define NL      4
#define NH      8
#define NP      4
#define HD      32        // HEAD_DIM
#define HMAX    128
#define WMAX    128
#define NLP     16        // NL*NP
#define NC      128       // NL*NP*NH
#define NOFF_AW 384       // 256 off cols + 128 attn cols
#define QPB     4         // queries per block in planner
#define BSTRIDE (HMAX*WMAX*NL*ED)   // 16,777,216 elements
#define XSTRIDE (WMAX*NL*ED)        // 131,072
#define YSTRIDE (NL*ED)             // 1,024
#define RPB     21760               // compact rows per batch: 128^2+64^2+32^2+16^2
#define TILES_PB 340                // 256+64+16+4 tiles per batch
#define RECPB   2097152             // record capacity per batch (4x mean per tile)
#define MAXB    4

typedef __attribute__((ext_vector_type(8))) __fp16   f16x8;
typedef __attribute__((ext_vector_type(4))) __fp16   f16x4;
typedef __attribute__((ext_vector_type(4))) float    f32x4;

__constant__ int LBASE_ROW[4] = {0, 16384, 20480, 21504};
__constant__ int TBASE[4]     = {0, 256, 320, 336};
// CAPL[l] = 2048 << (2*l); LRECBASE[l] = l * 524288; slice bits = 2*l

__device__ __forceinline__ unsigned pack2h(float a, float b) {
    union { __fp16 h[2]; unsigned u; } u;
    u.h[0] = (__fp16)a; u.h[1] = (__fp16)b; return u.u;
}

// ---------------- Kprep: V compaction + weight transpose + cursor zero ----
__global__ __launch_bounds__(1024) void msda_prep_kernel(
    const float* __restrict__ V,
    const float* __restrict__ W_off,
    const float* __restrict__ W_attn,
    const float* __restrict__ W_out,
    __fp16* __restrict__ Vc,
    __fp16* __restrict__ WcatT,
    __fp16* __restrict__ WoutT,
    unsigned* __restrict__ cursor,
    int nb, int nCompact, int nWconv)
{
    const int bid = blockIdx.x;
    const int t   = threadIdx.x;

    if (bid < nCompact) {
        const int r    = bid * 16 + (t >> 6);
        const int lane = t & 63;
        const int e    = lane << 2;
        const int total_rows = nb * RPB;
        if (r < total_rows) {
            const int b  = r / RPB;
            const int rr = r - b * RPB;
            int l, base;
            if (rr < 16384)      { l = 0; base = 0; }
            else if (rr < 20480) { l = 1; base = 16384; }
            else if (rr < 21504) { l = 2; base = 20480; }
            else                 { l = 3; base = 21504; }
            const int pos = rr - base;
            const int lsh = 7 - l;
            const int xi  = pos >> lsh;
            const int yi  = pos & ((1 << lsh) - 1);
            const float4 src = *(const float4*)&V[(size_t)b * BSTRIDE +
                (size_t)xi * XSTRIDE + (size_t)yi * YSTRIDE + l * ED + e];
            f16x4 d;
            d[0] = (__fp16)src.x; d[1] = (__fp16)src.y;
            d[2] = (__fp16)src.z; d[3] = (__fp16)src.w;
            *(f16x4*)&Vc[(size_t)r * 256 + e] = d;
        }
    } else if (bid < nCompact + nWconv) {
        const int idx = (bid - nCompact) * 1024 + t;
        const int t2 = NOFF_AW * ED;
        const int t3 = ED * ED;
        if (idx < t2) {
            int c = idx >> 8, e = idx & 255;
            float v = (c < ED) ? W_off[e * ED + c] : W_attn[e * NC + (c - ED)];
            WcatT[idx] = (__fp16)v;
        } else if (idx < t2 + t3) {
            int i = idx - t2;
            int c = i >> 8, e = i & 255;
            WoutT[i] = (__fp16)W_out[e * ED + c];
        }
    } else {
        for (int i = t; i < TILES_PB * nb; i += 1024) cursor[i] = 0u;
    }
}

// ------- K1: f16 2-pass MFMA GEMM: C = (Ah+Al) @ Bh^T + bias --------------
__global__ __launch_bounds__(256) void gemm_f16_kernel(
    const float*  __restrict__ A,
    const __fp16* __restrict__ BT,
    const float* __restrict__ bias0,
    const float* __restrict__ bias1,
    float* __restrict__ C,
    int M, int NTOT, int bias_split)
{
    const int wave = threadIdx.x >> 6;
    const int lane = threadIdx.x & 63;
    const int gw   = blockIdx.x * 4 + wave;
    const int ngroups = NTOT >> 6;
    const int mg = gw / ngroups, ng = gw % ngroups;
    const int m16 = mg * 16, n64 = ng * 64;
    if (m16 >= M) return;

    const int mrow = lane & 15;
    const int quad = lane >> 4;

    const float4* Arow = (const float4*)(A + (size_t)(m16 + mrow) * 256 + quad * 8);
    const f16x8* B0 = (const f16x8*)(BT + (size_t)(n64 +  0 + mrow) * 256 + quad * 8);
    const f16x8* B1 = (const f16x8*)(BT + (size_t)(n64 + 16 + mrow) * 256 + quad * 8);
    const f16x8* B2 = (const f16x8*)(BT + (size_t)(n64 + 32 + mrow) * 256 + quad * 8);
    const f16x8* B3 = (const f16x8*)(BT + (size_t)(n64 + 48 + mrow) * 256 + quad * 8);

    f32x4 acc0 = {0.f,0.f,0.f,0.f}, acc1 = acc0, acc2 = acc0, acc3 = acc0;
    #pragma unroll
    for (int kb = 0; kb < 8; ++kb) {
        float4 a0 = Arow[kb * 8 + 0];
        float4 a1 = Arow[kb * 8 + 1];
        float av[8] = {a0.x, a0.y, a0.z, a0.w, a1.x, a1.y, a1.z, a1.w};
        f16x8 ah, al;
        #pragma unroll
        for (int j = 0; j < 8; ++j) {
            __fp16 h = (__fp16)av[j];
            ah[j] = h;
            al[j] = (__fp16)(av[j] - (float)h);
        }
        f16x8 b0 = B0[kb * 4], b1 = B1[kb * 4], b2 = B2[kb * 4], b3 = B3[kb * 4];
        acc0 = __builtin_amdgcn_mfma_f32_16x16x32_f16(ah, b0, acc0, 0, 0, 0);
        acc1 = __builtin_amdgcn_mfma_f32_16x16x32_f16(ah, b1, acc1, 0, 0, 0);
        acc2 = __builtin_amdgcn_mfma_f32_16x16x32_f16(ah, b2, acc2, 0, 0, 0);
        acc3 = __builtin_amdgcn_mfma_f32_16x16x32_f16(ah, b3, acc3, 0, 0, 0);
        acc0 = __builtin_amdgcn_mfma_f32_16x16x32_f16(al, b0, acc0, 0, 0, 0);
        acc1 = __builtin_amdgcn_mfma_f32_16x16x32_f16(al, b1, acc1, 0, 0, 0);
        acc2 = __builtin_amdgcn_mfma_f32_16x16x32_f16(al, b2, acc2, 0, 0, 0);
        acc3 = __builtin_amdgcn_mfma_f32_16x16x32_f16(al, b3, acc3, 0, 0, 0);
    }

    const int col = lane & 15;
    f32x4 accs[4] = {acc0, acc1, acc2, acc3};
    #pragma unroll
    for (int i = 0; i < 4; ++i) {
        int n = n64 + i * 16 + col;
        float b = (n < bias_split) ? bias0[n] : bias1[n - bias_split];
        #pragma unroll
        for (int r = 0; r < 4; ++r) {
            int row = m16 + quad * 4 + r;
            C[(size_t)row * NTOT + n] = accs[i][r] + b;
        }
    }
}

// ---------------- K3: plain f16 MFMA GEMM ---------------------------------
__global__ __launch_bounds__(256) void gemm_ff16_kernel(
    const __fp16* __restrict__ A,
    const __fp16* __restrict__ BT,
    const float* __restrict__ bias,
    float* __restrict__ C,
    int M, int NTOT)
{
    const int wave = threadIdx.x >> 6;
    const int lane = threadIdx.x & 63;
    const int gw   = blockIdx.x * 4 + wave;
    const int ngroups = NTOT >> 6;
    const int mg = gw / ngroups, ng = gw % ngroups;
    const int m16 = mg * 16, n64 = ng * 64;
    if (m16 >= M) return;

    const int mrow = lane & 15;
    const int quad = lane >> 4;

    const f16x8* Arow = (const f16x8*)(A + (size_t)(m16 + mrow) * 256 + quad * 8);
    const f16x8* B0 = (const f16x8*)(BT + (size_t)(n64 +  0 + mrow) * 256 + quad * 8);
    const f16x8* B1 = (const f16x8*)(BT + (size_t)(n64 + 16 + mrow) * 256 + quad * 8);
    const f16x8* B2 = (const f16x8*)(BT + (size_t)(n64 + 32 + mrow) * 256 + quad * 8);
    const f16x8* B3 = (const f16x8*)(BT + (size_t)(n64 + 48 + mrow) * 256 + quad * 8);

    f32x4 acc0 = {0.f,0.f,0.f,0.f}, acc1 = acc0, acc2 = acc0, acc3 = acc0;
    #pragma unroll
    for (int kb = 0; kb < 8; ++kb) {
        f16x8 af = Arow[kb * 4];
        acc0 = __builtin_amdgcn_mfma_f32_16x16x32_f16(af, B0[kb * 4], acc0, 0, 0, 0);
        acc1 = __builtin_amdgcn_mfma_f32_16x16x32_f16(af, B1[kb * 4], acc1, 0, 0, 0);
        acc2 = __builtin_amdgcn_mfma_f32_16x16x32_f16(af, B2[kb * 4], acc2, 0, 0, 0);
        acc3 = __builtin_amdgcn_mfma_f32_16x16x32_f16(af, B3[kb * 4], acc3, 0, 0, 0);
    }

    const int col = lane & 15;
    f32x4 accs[4] = {acc0, acc1, acc2, acc3};
    #pragma unroll
    for (int i = 0; i < 4; ++i) {
        int n = n64 + i * 16 + col;
        float b = bias[n];
        #pragma unroll
        for (int r = 0; r < 4; ++r) {
            int row = m16 + quad * 4 + r;
            C[(size_t)row * NTOT + n] = accs[i][r] + b;
        }
    }
}

// ---------------- K2a: plan — params -> tile-binned records ---------------
__global__ __launch_bounds__(256) void msda_plan_kernel(
    const float*  __restrict__ refp,
    const __fp16* __restrict__ Vc,       // fallback only
    const float*  __restrict__ off_aw,   // (Q, 384)
    const int*    __restrict__ batch_off,
    int n_batch, int nb,
    unsigned* __restrict__ cursor,       // (340*nb)
    int4*     __restrict__ recB,
    __fp16*   __restrict__ sampled,      // fallback writes
    int nq)
{
    __shared__ float    law[QPB][NC];
    __shared__ float2   sminv[QPB][NH];
    __shared__ float2   sref[QPB];
    __shared__ unsigned hist[TILES_PB * MAXB];

    const int t  = threadIdx.x;
    const int q0 = blockIdx.x * QPB;
    const int tiles_total = TILES_PB * nb;

    for (int i = t; i < TILES_PB * MAXB; i += 256) hist[i] = 0u;

    {
        const int s = t >> 6, c = t & 63;
        const float* row = off_aw + (size_t)(q0 + s) * NOFF_AW + ED;
        law[s][c]      = row[c];
        law[s][c + 64] = row[c + 64];
    }
    __syncthreads();

    if (t < QPB * NH) {
        const int s = t >> 3, h = t & 7;
        float m = -1e30f;
        #pragma unroll
        for (int lp = 0; lp < NLP; ++lp) m = fmaxf(m, law[s][lp * NH + h]);
        float sum = 0.f;
        #pragma unroll
        for (int lp = 0; lp < NLP; ++lp) sum += __expf(law[s][lp * NH + h] - m);
        sminv[s][h] = make_float2(m, 1.f / sum);
    } else if (t < QPB * NH + QPB) {
        const int s = t - QPB * NH;
        const int qid = q0 + s;
        float rx = refp[qid * 2 + 0], ry = refp[qid * 2 + 1];
        rx = fminf(fmaxf(rx, 0.f), 1.f);
        ry = fminf(fmaxf(ry, 0.f), 1.f);
        float ivx = __logf(fmaxf(rx, 1e-5f) / fmaxf(1.f - rx, 1e-5f));
        float ivy = __logf(fmaxf(ry, 1e-5f) / fmaxf(1.f - ry, 1e-5f));
        sref[s] = make_float2(ivx, ivy);
    }
    __syncthreads();

    // ---- compute both samples for this thread ----
    const int s = t >> 6;
    const int qid = q0 + s;
    int b = 0;
    for (int i = 1; i < n_batch; ++i)
        if (batch_off[i] <= qid) b = i;
    const float2 iv = sref[s];
    const float* offrow = off_aw + (size_t)qid * NOFF_AW;

    int4   rec[2];
    int    tileg[2];
    float4 wf[2];
    int    gx0[2], gy0[2], gx1[2], gy1[2];

    #pragma unroll
    for (int half = 0; half < 2; ++half) {
        const int c = (t & 63) + half * 64;
        const int l = c >> 5;
        const int h = c & 7;
        const int lsh = 7 - l;
        const int sz  = 1 << lsh;
        const int cap = sz - 1;

        const float2 mi = sminv[s][h];
        const float a = __expf(law[s][c] - mi.x) * mi.y;

        const float ox = offrow[c * 2 + 0], oy = offrow[c * 2 + 1];
        float lx = 2.f / (1.f + __expf(-(iv.x + ox))) - 1.f;
        float ly = 2.f / (1.f + __expf(-(iv.y + oy))) - 1.f;
        float x = ((lx + 1.f) * (float)sz - 1.f) * 0.5f;
        float y = ((ly + 1.f) * (float)sz - 1.f) * 0.5f;
        int x0 = (int)floorf(x), y0 = (int)floorf(y);
        int x1 = x0 + 1, y1 = y0 + 1;
        x0 = min(max(x0, 0), cap); x1 = min(max(x1, 0), cap);
        y0 = min(max(y0, 0), cap); y1 = min(max(y1, 0), cap);
        float x0f = (float)x0, x1f = (float)x1;
        float y0f = (float)y0, y1f = (float)y1;

        float4 w;
        w.x = a * (x1f - x) * (y1f - y);   // (x0,y0)
        w.y = a * (x1f - x) * (y - y0f);   // (x0,y1)
        w.z = a * (x - x0f) * (y1f - y);   // (x1,y0)
        w.w = a * (x - x0f) * (y - y0f);   // (x1,y1)

        const int ntr = sz >> 3;
        const int tx = x0 >> 3, ty = y0 >> 3;
        const int til = b * TILES_PB + TBASE[l] + tx * ntr + ty;
        tileg[half] = til;
        wf[half] = w;
        gx0[half] = x0; gy0[half] = y0; gx1[half] = x1; gy1[half] = y1;
        rec[half].x = (qid << 7) | c;      // dest
        rec[half].y = (x0 - (tx << 3)) | ((y0 - (ty << 3)) << 4) |
                      ((x1 - (tx << 3)) << 8) | ((y1 - (ty << 3)) << 12);
        rec[half].z = (int)pack2h(w.x, w.y);
        rec[half].w = (int)pack2h(w.z, w.w);
        atomicAdd(&hist[til], 1u);
    }
    __syncthreads();

    // ---- reserve global ranges per tile touched by this block ----
    for (int i = t; i < tiles_total; i += 256) {
        unsigned cloc = hist[i];
        hist[i] = (cloc > 0u) ? atomicAdd(&cursor[i], cloc) : 0u;
    }
    __syncthreads();

    // ---- emit records (or fallback gather on overflow) ----
    #pragma unroll
    for (int half = 0; half < 2; ++half) {
        const int til = tileg[half];
        const unsigned pos = atomicAdd(&hist[til], 1u);
        const int c = rec[half].x & 127;
        const int l = c >> 5;
        const unsigned capl = 2048u << (2 * l);
        if (pos < capl) {
            const int b2  = til / TILES_PB;
            const int tin = til - b2 * TILES_PB - TBASE[l];
            recB[(size_t)b2 * RECPB + (size_t)l * 524288 +
                 (size_t)tin * capl + pos] = rec[half];
        } else {
            // rare fallback: direct gather from Vc
            const int h = c & 7;
            const int lsh = 7 - l, sz = 1 << lsh;
            const int rowb = b * RPB + LBASE_ROW[l];
            const int dest = rec[half].x;
            const float4 w = wf[half];
            const __fp16* p00 = Vc + ((size_t)(rowb + gx0[half]*sz + gy0[half]))*256 + h*HD;
            const __fp16* p01 = Vc + ((size_t)(rowb + gx0[half]*sz + gy1[half]))*256 + h*HD;
            const __fp16* p10 = Vc + ((size_t)(rowb + gx1[half]*sz + gy0[half]))*256 + h*HD;
            const __fp16* p11 = Vc + ((size_t)(rowb + gx1[half]*sz + gy1[half]))*256 + h*HD;
            for (int d = 0; d < HD; ++d) {
                float v = w.x*(float)p00[d] + w.y*(float)p01[d]
                        + w.z*(float)p10[d] + w.w*(float)p11[d];
                sampled[(size_t)dest * HD + d] = (__fp16)v;
            }
        }
    }
}

// ---------------- K2d: per-tile LDS gather --------------------------------
__global__ __launch_bounds__(256) void msda_tile_kernel(
    const __fp16*   __restrict__ Vc,
    const unsigned* __restrict__ cursor,
    const int4*     __restrict__ recB,
    __fp16*         __restrict__ sampled)
{
    __shared__ __fp16 patch[81 * 264];   // 9x9 rows, stride 264 (bank rotate)

    const int bid = blockIdx.x;
    const int b   = bid >> 10;           // 1024 slots per batch
    const int sid = bid & 1023;
    const int l   = sid >> 8;
    const int s2  = sid & 255;
    const int sbits = 2 * l;
    const int tin   = s2 >> sbits;
    const int slice = s2 & ((1 << sbits) - 1);
    const int lsh = 7 - l, sz = 1 << lsh, ntr = sz >> 3, cap = sz - 1;
    const int tx = tin / ntr, ty = tin - tx * ntr;
    const int x0b = tx << 3, y0b = ty << 3;
    const int rowb = b * RPB + LBASE_ROW[l];

    const int wv = threadIdx.x >> 6, lane = threadIdx.x & 63;

    for (int r = wv; r < 81; r += 4) {
        const int xi = r / 9, yi = r - xi * 9;
        const int gx = x0b + xi, gy = y0b + yi;
        if (gx <= cap && gy <= cap) {
            f16x4 v = *(const f16x4*)&Vc[((size_t)(rowb + gx * sz + gy)) * 256 + lane * 4];
            *(f16x4*)&patch[r * 264 + lane * 4] = v;
        }
    }
    __syncthreads();

    const int tglob = b * TILES_PB + TBASE[l] + tin;
    unsigned cnt = cursor[tglob];
    const unsigned capl = 2048u << sbits;   // 2048 << 2l
    if (cnt > capl) cnt = capl;
    const int nsl = 1 << sbits;
    const unsigned per = (cnt + (unsigned)nsl - 1u) >> sbits;
    const unsigned lo = (unsigned)slice * per;
    unsigned hi = lo + per; if (hi > cnt) hi = cnt;

    const int4* recT = recB + (size_t)b * RECPB + (size_t)l * 524288 +
                       (size_t)tin * capl;
    const int g = lane >> 3, j = lane & 7;

    for (unsigned base = lo + (unsigned)wv * 8u; base < hi; base += 32u) {
        const unsigned idx = base + (unsigned)g;
        if (idx < hi) {
            int4 rec = recT[idx];
            const int dest = rec.x;
            const int db = (dest & 7) * HD + j * 4;
            const int lx0 = rec.y & 15, ly0 = (rec.y >> 4) & 15;
            const int lx1 = (rec.y >> 8) & 15, ly1 = (rec.y >> 12) & 15;
            union { unsigned u; __fp16 h[2]; } pA, pB;
            pA.u = (unsigned)rec.z; pB.u = (unsigned)rec.w;
            const float w0 = (float)pA.h[0], w1 = (float)pA.h[1];
            const float w2 = (float)pB.h[0], w3 = (float)pB.h[1];
            f16x4 p00 = *(f16x4*)&patch[(lx0 * 9 + ly0) * 264 + db];
            f16x4 p01 = *(f16x4*)&patch[(lx0 * 9 + ly1) * 264 + db];
            f16x4 p10 = *(f16x4*)&patch[(lx1 * 9 + ly0) * 264 + db];
            f16x4 p11 = *(f16x4*)&patch[(lx1 * 9 + ly1) * 264 + db];
            f16x4 o;
            #pragma unroll
            for (int k = 0; k < 4; ++k)
                o[k] = (__fp16)(w0*(float)p00[k] + w1*(float)p01[k] +
                                w2*(float)p10[k] + w3*(float)p11[k]);
            *(f16x4*)&sampled[(size_t)dest * HD + j * 4] = o;
        }
    }
}

// ---------------- K2e: reduce 16 points per (q,h) -> out_pre --------------
__global__ __launch_bounds__(256) void msda_reduce_kernel(
    const __fp16* __restrict__ sampled,
    __fp16* __restrict__ out_pre)
{
    const int t = threadIdx.x;
    const int grp = t >> 3, j = t & 7;
    const int gid = blockIdx.x * 32 + grp;   // q*8 + h
    const int q = gid >> 3, h = gid & 7;
    float acc0 = 0.f, acc1 = 0.f, acc2 = 0.f, acc3 = 0.f;
    #pragma unroll
    for (int lp = 0; lp < NLP; ++lp) {
        f16x4 v = *(const f16x4*)&sampled[((size_t)(q * 128 + lp * 8 + h)) * HD + j * 4];
        acc0 += (float)v[0]; acc1 += (float)v[1];
        acc2 += (float)v[2]; acc3 += (float)v[3];
    }
    f16x4 o;
    o[0] = (__fp16)acc0; o[1] = (__fp16)acc1;
    o[2] = (__fp16)acc2; o[3] = (__fp16)acc3;
    *(f16x4*)&out_pre[(size_t)q * ED + h * HD + j * 4] = o;
}

extern "C" void kernel_launch(void* const* d_in, const int* in_sizes, int n_in,
                              void* d_out, int out_size, void* d_ws, size_t ws_size,
                              hipStream_t stream) {
    const float* query  = (const float*)d_in[0];
    const float* refp   = (const float*)d_in[1];
    const float* V      = (const float*)d_in[2];
    const float* W_off  = (const float*)d_in[3];
    const float* b_off  = (const float*)d_in[4];
    const float* W_attn = (const float*)d_in[5];
    const float* b_attn = (const float*)d_in[6];
    const float* W_out  = (const float*)d_in[7];
    const float* b_out  = (const float*)d_in[8];
    const int*   boff   = (const int*)d_in[9];
    const int n_batch   = in_sizes[9];
    const int nq        = in_sizes[0] / ED;
    const int nb        = in_sizes[2] / BSTRIDE;
    float* out = (float*)d_out;

    // workspace layout (16B-aligned chunks)
    char* ws = (char*)d_ws;
    float*    off_aw  = (float*)ws;                               // nq*384 f32
    __fp16*   WcatT   = (__fp16*)(off_aw + (size_t)nq * NOFF_AW); // 384*256
    __fp16*   WoutT   = WcatT + NOFF_AW * ED;                     // 256*256
    __fp16*   out_pre = WoutT + ED * ED;                          // nq*256
    __fp16*   Vc      = out_pre + (size_t)nq * ED;                // nb*RPB*256
    unsigned* cursor  = (unsigned*)(Vc + (size_t)nb * RPB * 256); // 340*nb
    char*     aligned = (char*)(cursor + TILES_PB * MAXB);
    aligned = (char*)(((size_t)aligned + 15) & ~(size_t)15);
    int4*     recB    = (int4*)aligned;                           // nb*RECPB*16B
    __fp16*   sampled = (__fp16*)(recB + (size_t)nb * RECPB);     // nq*128*32

    // Kprep: compact V + weights + zero cursors
    {
        int nCompact = (nb * RPB + 15) / 16;
        int nWconv   = (NOFF_AW * ED + ED * ED + 1023) / 1024;
        msda_prep_kernel<<<nCompact + nWconv + 1, 1024, 0, stream>>>(
            V, W_off, W_attn, W_out, Vc, WcatT, WoutT, cursor,
            nb, nCompact, nWconv);
    }
    // K1: [off|aw] = q @ [W_off|W_attn] + bias
    {
        int waves = (nq / 16) * (NOFF_AW / 64);
        gemm_f16_kernel<<<(waves + 3) / 4, 256, 0, stream>>>(
            query, WcatT, b_off, b_attn, off_aw, nq, NOFF_AW, ED);
    }
    // K2a: plan (params -> binned records)
    msda_plan_kernel<<<nq / QPB, 256, 0, stream>>>(
        refp, Vc, off_aw, boff, n_batch, nb, cursor, recB, sampled, nq);
    // K2d: per-tile LDS gather
    msda_tile_kernel<<<nb * 1024, 256, 0, stream>>>(Vc, cursor, recB, sampled);
    // K2e: reduce -> out_pre
    msda_reduce_kernel<<<nq / 4, 256, 0, stream>>>(sampled, out_pre);
    // K3: out = out_pre @ W_out + b_out
    {
        int waves = (nq / 16) * (ED / 64);
        gemm_ff16_kernel<<<(waves + 3) / 4, 256, 0, stream>>>(
            out_pre, WoutT, b_out, out, nq, ED);
    }
}

// Round 9
// 279.410 us; speedup vs baseline: 1.2115x; 1.2115x over previous
//
#include <hip/hip_runtime.h>
#include <math.h>

#define ED      256       // EMBED_DIM
#define NL      4
#define NH      8
#define NP      4
#define HD      32        // HEAD_DIM
#define HMAX    128
#define WMAX    128
#define NLP     16        // NL*NP
#define NC      128       // NL*NP*NH
#define NOFF_AW 384       // 256 off cols + 128 attn cols
#define QPB     4         // queries per block in sampler
#define NBK     1024      // sort buckets
#define BSTRIDE (HMAX*WMAX*NL*ED)   // 16,777,216 elements
#define XSTRIDE (WMAX*NL*ED)        // 131,072
#define YSTRIDE (NL*ED)             // 1,024
#define RPB     21760               // compact rows per batch: 128^2+64^2+32^2+16^2
#define PBC     (RPB*256)           // compact elems per batch

typedef __attribute__((ext_vector_type(8))) __fp16   f16x8;
typedef __attribute__((ext_vector_type(4))) __fp16   f16x4;
typedef __attribute__((ext_vector_type(4))) float    f32x4;

__constant__ int LBASE_ROW[4] = {0, 16384, 20480, 21504};

// ---------------- Kprep: V compaction (f32->f16, drop masked zeros) -------
//                + weight transpose/convert + query locality sort ----------
__global__ __launch_bounds__(1024) void msda_prep_kernel(
    const float* __restrict__ V,
    const float* __restrict__ W_off,
    const float* __restrict__ W_attn,
    const float* __restrict__ W_out,
    const float* __restrict__ refp,
    const int*   __restrict__ batch_off,
    int n_batch,
    __fp16* __restrict__ Vc,
    __fp16* __restrict__ WcatT,
    __fp16* __restrict__ WoutT,
    int* __restrict__ bucket_of,
    int* __restrict__ perm,
    int nq, int nb, int nCompact, int nWconv)
{
    __shared__ int cnt[NBK];
    __shared__ int scan[NBK];
    const int bid = blockIdx.x;
    const int t   = threadIdx.x;

    if (bid < nCompact) {
        const int r    = bid * 16 + (t >> 6);
        const int lane = t & 63;
        const int e    = lane << 2;
        const int total_rows = nb * RPB;
        if (r < total_rows) {
            const int b  = r / RPB;
            const int rr = r - b * RPB;
            int l, base;
            if (rr < 16384)      { l = 0; base = 0; }
            else if (rr < 20480) { l = 1; base = 16384; }
            else if (rr < 21504) { l = 2; base = 20480; }
            else                 { l = 3; base = 21504; }
            const int pos = rr - base;
            const int lsh = 7 - l;
            const int xi  = pos >> lsh;
            const int yi  = pos & ((1 << lsh) - 1);
            const float4 src = *(const float4*)&V[(size_t)b * BSTRIDE +
                (size_t)xi * XSTRIDE + (size_t)yi * YSTRIDE + l * ED + e];
            f16x4 d;
            d[0] = (__fp16)src.x; d[1] = (__fp16)src.y;
            d[2] = (__fp16)src.z; d[3] = (__fp16)src.w;
            *(f16x4*)&Vc[(size_t)r * 256 + e] = d;
        }
    } else if (bid < nCompact + nWconv) {
        const int idx = (bid - nCompact) * 1024 + t;
        const int t2 = NOFF_AW * ED;
        const int t3 = ED * ED;
        if (idx < t2) {
            int c = idx >> 8, e = idx & 255;
            float v = (c < ED) ? W_off[e * ED + c] : W_attn[e * NC + (c - ED)];
            WcatT[idx] = (__fp16)v;
        } else if (idx < t2 + t3) {
            int i = idx - t2;
            int c = i >> 8, e = i & 255;
            WoutT[i] = (__fp16)W_out[e * ED + c];
        }
    } else {
        // ---- locality sort: bucket by (batch, 16x16 ref tile) ----
        cnt[t] = 0;
        __syncthreads();
        const int iters = (nq + 1023) >> 10;
        for (int i = 0; i < iters; ++i) {
            int q = i * 1024 + t;
            if (q < nq) {
                int b = 0;
                for (int j = 1; j < n_batch; ++j)
                    if (batch_off[j] <= q) b = j;
                b = min(b, 3);
                float rx = refp[q * 2 + 0], ry = refp[q * 2 + 1];
                int bx = min(15, max(0, (int)(rx * 16.f)));
                int by = min(15, max(0, (int)(ry * 16.f)));
                int bk = (b << 8) | (by << 4) | bx;
                bucket_of[q] = bk;
                atomicAdd(&cnt[bk], 1);
            }
        }
        __syncthreads();
        scan[t] = cnt[t];
        __syncthreads();
        for (int d = 1; d < NBK; d <<= 1) {
            int v = scan[t];
            int u = (t >= d) ? scan[t - d] : 0;
            __syncthreads();
            scan[t] = v + u;
            __syncthreads();
        }
        cnt[t] = scan[t] - cnt[t];
        __syncthreads();
        for (int i = 0; i < iters; ++i) {
            int q = i * 1024 + t;
            if (q < nq) {
                int bk = bucket_of[q];
                int pos = atomicAdd(&cnt[bk], 1);
                perm[pos] = q;
            }
        }
    }
}

// ------- K1: f16 2-pass MFMA GEMM: C = (Ah+Al) @ Bh^T + bias --------------
__global__ __launch_bounds__(256) void gemm_f16_kernel(
    const float*  __restrict__ A,     // (M,256) f32
    const __fp16* __restrict__ BT,    // (NTOT,256) f16
    const float* __restrict__ bias0,
    const float* __restrict__ bias1,
    float* __restrict__ C,
    int M, int NTOT, int bias_split)
{
    const int wave = threadIdx.x >> 6;
    const int lane = threadIdx.x & 63;
    const int gw   = blockIdx.x * 4 + wave;
    const int ngroups = NTOT >> 6;
    const int mg = gw / ngroups, ng = gw % ngroups;
    const int m16 = mg * 16, n64 = ng * 64;
    if (m16 >= M) return;

    const int mrow = lane & 15;
    const int quad = lane >> 4;

    const float4* Arow = (const float4*)(A + (size_t)(m16 + mrow) * 256 + quad * 8);
    const f16x8* B0 = (const f16x8*)(BT + (size_t)(n64 +  0 + mrow) * 256 + quad * 8);
    const f16x8* B1 = (const f16x8*)(BT + (size_t)(n64 + 16 + mrow) * 256 + quad * 8);
    const f16x8* B2 = (const f16x8*)(BT + (size_t)(n64 + 32 + mrow) * 256 + quad * 8);
    const f16x8* B3 = (const f16x8*)(BT + (size_t)(n64 + 48 + mrow) * 256 + quad * 8);

    f32x4 acc0 = {0.f,0.f,0.f,0.f}, acc1 = acc0, acc2 = acc0, acc3 = acc0;
    #pragma unroll
    for (int kb = 0; kb < 8; ++kb) {
        float4 a0 = Arow[kb * 8 + 0];
        float4 a1 = Arow[kb * 8 + 1];
        float av[8] = {a0.x, a0.y, a0.z, a0.w, a1.x, a1.y, a1.z, a1.w};
        f16x8 ah, al;
        #pragma unroll
        for (int j = 0; j < 8; ++j) {
            __fp16 h = (__fp16)av[j];
            ah[j] = h;
            al[j] = (__fp16)(av[j] - (float)h);
        }
        f16x8 b0 = B0[kb * 4], b1 = B1[kb * 4], b2 = B2[kb * 4], b3 = B3[kb * 4];
        acc0 = __builtin_amdgcn_mfma_f32_16x16x32_f16(ah, b0, acc0, 0, 0, 0);
        acc1 = __builtin_amdgcn_mfma_f32_16x16x32_f16(ah, b1, acc1, 0, 0, 0);
        acc2 = __builtin_amdgcn_mfma_f32_16x16x32_f16(ah, b2, acc2, 0, 0, 0);
        acc3 = __builtin_amdgcn_mfma_f32_16x16x32_f16(ah, b3, acc3, 0, 0, 0);
        acc0 = __builtin_amdgcn_mfma_f32_16x16x32_f16(al, b0, acc0, 0, 0, 0);
        acc1 = __builtin_amdgcn_mfma_f32_16x16x32_f16(al, b1, acc1, 0, 0, 0);
        acc2 = __builtin_amdgcn_mfma_f32_16x16x32_f16(al, b2, acc2, 0, 0, 0);
        acc3 = __builtin_amdgcn_mfma_f32_16x16x32_f16(al, b3, acc3, 0, 0, 0);
    }

    const int col = lane & 15;
    f32x4 accs[4] = {acc0, acc1, acc2, acc3};
    #pragma unroll
    for (int i = 0; i < 4; ++i) {
        int n = n64 + i * 16 + col;
        float b = (n < bias_split) ? bias0[n] : bias1[n - bias_split];
        #pragma unroll
        for (int r = 0; r < 4; ++r) {
            int row = m16 + quad * 4 + r;
            C[(size_t)row * NTOT + n] = accs[i][r] + b;
        }
    }
}

// ---------------- K3: plain f16 MFMA GEMM ---------------------------------
__global__ __launch_bounds__(256) void gemm_ff16_kernel(
    const __fp16* __restrict__ A,     // (M,256) f16
    const __fp16* __restrict__ BT,    // (NTOT,256) f16
    const float* __restrict__ bias,
    float* __restrict__ C,
    int M, int NTOT)
{
    const int wave = threadIdx.x >> 6;
    const int lane = threadIdx.x & 63;
    const int gw   = blockIdx.x * 4 + wave;
    const int ngroups = NTOT >> 6;
    const int mg = gw / ngroups, ng = gw % ngroups;
    const int m16 = mg * 16, n64 = ng * 64;
    if (m16 >= M) return;

    const int mrow = lane & 15;
    const int quad = lane >> 4;

    const f16x8* Arow = (const f16x8*)(A + (size_t)(m16 + mrow) * 256 + quad * 8);
    const f16x8* B0 = (const f16x8*)(BT + (size_t)(n64 +  0 + mrow) * 256 + quad * 8);
    const f16x8* B1 = (const f16x8*)(BT + (size_t)(n64 + 16 + mrow) * 256 + quad * 8);
    const f16x8* B2 = (const f16x8*)(BT + (size_t)(n64 + 32 + mrow) * 256 + quad * 8);
    const f16x8* B3 = (const f16x8*)(BT + (size_t)(n64 + 48 + mrow) * 256 + quad * 8);

    f32x4 acc0 = {0.f,0.f,0.f,0.f}, acc1 = acc0, acc2 = acc0, acc3 = acc0;
    #pragma unroll
    for (int kb = 0; kb < 8; ++kb) {
        f16x8 af = Arow[kb * 4];
        acc0 = __builtin_amdgcn_mfma_f32_16x16x32_f16(af, B0[kb * 4], acc0, 0, 0, 0);
        acc1 = __builtin_amdgcn_mfma_f32_16x16x32_f16(af, B1[kb * 4], acc1, 0, 0, 0);
        acc2 = __builtin_amdgcn_mfma_f32_16x16x32_f16(af, B2[kb * 4], acc2, 0, 0, 0);
        acc3 = __builtin_amdgcn_mfma_f32_16x16x32_f16(af, B3[kb * 4], acc3, 0, 0, 0);
    }

    const int col = lane & 15;
    f32x4 accs[4] = {acc0, acc1, acc2, acc3};
    #pragma unroll
    for (int i = 0; i < 4; ++i) {
        int n = n64 + i * 16 + col;
        float b = bias[n];
        #pragma unroll
        for (int r = 0; r < 4; ++r) {
            int row = m16 + quad * 4 + r;
            C[(size_t)row * NTOT + n] = accs[i][r] + b;
        }
    }
}

// ---------------- K2: softmax + sampling + bilinear gather (compact V) ----
// Level-0 corner loads are NON-TEMPORAL: no L2 allocation, so levels 1-3
// (2.7 MB compact) stay L2-resident -> ~75% of gather requests L2-hit.
__global__ __launch_bounds__(256, 8) void msda_sample_kernel(
    const float*  __restrict__ refp,     // (Q, 2)
    const __fp16* __restrict__ Vc,       // compact f16 value tensor
    const float*  __restrict__ off_aw,   // (Q, 384)
    const int*    __restrict__ perm,     // (Q) locality-sorted ids
    const int*    __restrict__ batch_off,
    int n_batch,
    __fp16* __restrict__ out_pre,        // (Q, 256) f16
    int q_total)
{
    __shared__ int    sqid[QPB];
    __shared__ float  law[QPB][NC];
    __shared__ float2 sminv[QPB][NH];
    __shared__ float2 sref[QPB];
    __shared__ int4   soff[QPB][NC];
    __shared__ float4 swt[QPB][NC];

    const int t = threadIdx.x;
    const int chunk = gridDim.x >> 3;
    const int pblk  = (blockIdx.x & 7) * chunk + (blockIdx.x >> 3);
    const int q0 = pblk * QPB;

    if (t < QPB) sqid[t] = perm[q0 + t];
    __syncthreads();

    // ---- load attn logits ----
    {
        const int s = t >> 6, c = t & 63;
        const float* row = off_aw + (size_t)sqid[s] * NOFF_AW + ED;
        law[s][c]      = row[c];
        law[s][c + 64] = row[c + 64];
    }
    __syncthreads();

    // ---- softmax stats + ref-point prep ----
    if (t < QPB * NH) {
        const int s = t >> 3, h = t & 7;
        float m = -1e30f;
        #pragma unroll
        for (int lp = 0; lp < NLP; ++lp) m = fmaxf(m, law[s][lp * NH + h]);
        float sum = 0.f;
        #pragma unroll
        for (int lp = 0; lp < NLP; ++lp) sum += __expf(law[s][lp * NH + h] - m);
        sminv[s][h] = make_float2(m, 1.f / sum);
    } else if (t < QPB * NH + QPB) {
        const int s = t - QPB * NH;
        const int qid = sqid[s];
        float rx = refp[qid * 2 + 0], ry = refp[qid * 2 + 1];
        rx = fminf(fmaxf(rx, 0.f), 1.f);
        ry = fminf(fmaxf(ry, 0.f), 1.f);
        float ivx = __logf(fmaxf(rx, 1e-5f) / fmaxf(1.f - rx, 1e-5f));
        float ivy = __logf(fmaxf(ry, 1e-5f) / fmaxf(1.f - ry, 1e-5f));
        sref[s] = make_float2(ivx, ivy);
    }
    __syncthreads();

    // ---- sampling params (compact offsets): thread does c and c+64 ----
    {
        const int s = t >> 6;
        const int qid = sqid[s];
        int b = 0;
        for (int i = 1; i < n_batch; ++i)
            if (batch_off[i] <= qid) b = i;
        const int cb = b * PBC;
        const float2 iv = sref[s];
        const float* offrow = off_aw + (size_t)qid * NOFF_AW;

        #pragma unroll
        for (int half = 0; half < 2; ++half) {
            const int c = (t & 63) + half * 64;
            const int l = c >> 5;
            const int lsh = 7 - l;
            const int sz  = 1 << lsh;
            const int cap = sz - 1;
            const int h = c & 7;

            const float2 mi = sminv[s][h];
            const float a = __expf(law[s][c] - mi.x) * mi.y;

            const float ox = offrow[c * 2 + 0], oy = offrow[c * 2 + 1];
            float lx = 2.f / (1.f + __expf(-(iv.x + ox))) - 1.f;
            float ly = 2.f / (1.f + __expf(-(iv.y + oy))) - 1.f;
            float x = ((lx + 1.f) * (float)sz - 1.f) * 0.5f;
            float y = ((ly + 1.f) * (float)sz - 1.f) * 0.5f;
            int x0 = (int)floorf(x), y0 = (int)floorf(y);
            int x1 = x0 + 1, y1 = y0 + 1;
            x0 = min(max(x0, 0), cap); x1 = min(max(x1, 0), cap);
            y0 = min(max(y0, 0), cap); y1 = min(max(y1, 0), cap);
            float x0f = (float)x0, x1f = (float)x1;
            float y0f = (float)y0, y1f = (float)y1;

            float4 w;
            w.x = a * (x1f - x) * (y1f - y);
            w.y = a * (x1f - x) * (y - y0f);
            w.z = a * (x - x0f) * (y1f - y);
            w.w = a * (x - x0f) * (y - y0f);
            swt[s][c] = w;
            const int lb = cb + (LBASE_ROW[l] << 8);
            int4 o;
            o.x = lb + (((x0 << lsh) + y0) << 8);
            o.y = lb + (((x0 << lsh) + y1) << 8);
            o.z = lb + (((x1 << lsh) + y0) << 8);
            o.w = lb + (((x1 << lsh) + y1) << 8);
            soff[s][c] = o;
        }
    }
    __syncthreads();

    // ---- gather: one wave per query; lane = (h, d4); f16x4 corners ----
    {
        const int s    = t >> 6;
        const int lane = t & 63;
        const int h    = lane >> 3;
        const int d4   = (lane & 7) << 2;
        const int inner = h * HD + d4;
        float4 acc = {0.f, 0.f, 0.f, 0.f};

        // level 0 (lp 0..3): non-temporal — bypass L2 allocation
        #pragma unroll
        for (int lp = 0; lp < 4; ++lp) {
            const int c = lp * NH + h;
            int4   o = soff[s][c];
            float4 w = swt[s][c];
            f16x4 v0 = __builtin_nontemporal_load((const f16x4*)&Vc[o.x + inner]);
            f16x4 v1 = __builtin_nontemporal_load((const f16x4*)&Vc[o.y + inner]);
            f16x4 v2 = __builtin_nontemporal_load((const f16x4*)&Vc[o.z + inner]);
            f16x4 v3 = __builtin_nontemporal_load((const f16x4*)&Vc[o.w + inner]);
            acc.x += w.x*(float)v0[0] + w.y*(float)v1[0] + w.z*(float)v2[0] + w.w*(float)v3[0];
            acc.y += w.x*(float)v0[1] + w.y*(float)v1[1] + w.z*(float)v2[1] + w.w*(float)v3[1];
            acc.z += w.x*(float)v0[2] + w.y*(float)v1[2] + w.z*(float)v2[2] + w.w*(float)v3[2];
            acc.w += w.x*(float)v0[3] + w.y*(float)v1[3] + w.z*(float)v2[3] + w.w*(float)v3[3];
        }
        // levels 1-3 (lp 4..15): normal loads — keep L2-resident (2.7 MB)
        #pragma unroll 4
        for (int lp = 4; lp < NLP; ++lp) {
            const int c = lp * NH + h;
            int4   o = soff[s][c];
            float4 w = swt[s][c];
            f16x4 v0 = *(const f16x4*)&Vc[o.x + inner];
            f16x4 v1 = *(const f16x4*)&Vc[o.y + inner];
            f16x4 v2 = *(const f16x4*)&Vc[o.z + inner];
            f16x4 v3 = *(const f16x4*)&Vc[o.w + inner];
            acc.x += w.x*(float)v0[0] + w.y*(float)v1[0] + w.z*(float)v2[0] + w.w*(float)v3[0];
            acc.y += w.x*(float)v0[1] + w.y*(float)v1[1] + w.z*(float)v2[1] + w.w*(float)v3[1];
            acc.z += w.x*(float)v0[2] + w.y*(float)v1[2] + w.z*(float)v2[2] + w.w*(float)v3[2];
            acc.w += w.x*(float)v0[3] + w.y*(float)v1[3] + w.z*(float)v2[3] + w.w*(float)v3[3];
        }
        f16x4 o4;
        o4[0] = (__fp16)acc.x; o4[1] = (__fp16)acc.y;
        o4[2] = (__fp16)acc.z; o4[3] = (__fp16)acc.w;
        *(f16x4*)&out_pre[(size_t)sqid[s] * ED + inner] = o4;
    }
}

extern "C" void kernel_launch(void* const* d_in, const int* in_sizes, int n_in,
                              void* d_out, int out_size, void* d_ws, size_t ws_size,
                              hipStream_t stream) {
    const float* query  = (const float*)d_in[0];
    const float* refp   = (const float*)d_in[1];
    const float* V      = (const float*)d_in[2];
    const float* W_off  = (const float*)d_in[3];
    const float* b_off  = (const float*)d_in[4];
    const float* W_attn = (const float*)d_in[5];
    const float* b_attn = (const float*)d_in[6];
    const float* W_out  = (const float*)d_in[7];
    const float* b_out  = (const float*)d_in[8];
    const int*   boff   = (const int*)d_in[9];
    const int n_batch   = in_sizes[9];
    const int nq        = in_sizes[0] / ED;
    const int nb        = in_sizes[2] / BSTRIDE;
    float* out = (float*)d_out;

    // workspace layout (all chunks 16B-aligned)
    char* ws = (char*)d_ws;
    float*   off_aw    = (float*)ws;                             // nq*384 f32
    int*     perm      = (int*)(off_aw + (size_t)nq * NOFF_AW);  // nq int
    int*     bucket_of = perm + nq;                              // nq int
    __fp16*  WcatT     = (__fp16*)(bucket_of + nq);              // 384*256 f16
    __fp16*  WoutT     = WcatT + NOFF_AW * ED;                   // 256*256 f16
    __fp16*  out_pre   = WoutT + ED * ED;                        // nq*256 f16
    __fp16*  Vc        = out_pre + (size_t)nq * ED;              // nb*RPB*256 f16

    // Kprep: V compaction + weight conversion + locality sort
    {
        int nCompact = (nb * RPB + 15) / 16;
        int nWconv   = (NOFF_AW * ED + ED * ED + 1023) / 1024;
        msda_prep_kernel<<<nCompact + nWconv + 1, 1024, 0, stream>>>(
            V, W_off, W_attn, W_out, refp, boff, n_batch,
            Vc, WcatT, WoutT, bucket_of, perm, nq, nb, nCompact, nWconv);
    }
    // K1: [off|aw] = q @ [W_off|W_attn] + bias  (f16 2-pass, A exact)
    {
        int waves = (nq / 16) * (NOFF_AW / 64);
        gemm_f16_kernel<<<(waves + 3) / 4, 256, 0, stream>>>(
            query, WcatT, b_off, b_attn, off_aw, nq, NOFF_AW, ED);
    }
    // K2: sampling + gather (compact f16 V, nt on level 0) -> out_pre
    {
        msda_sample_kernel<<<nq / QPB, 256, 0, stream>>>(
            refp, Vc, off_aw, perm, boff, n_batch, out_pre, nq);
    }
    // K3: out = out_pre @ W_out + b_out
    {
        int waves = (nq / 16) * (ED / 64);
        gemm_ff16_kernel<<<(waves + 3) / 4, 256, 0, stream>>>(
            out_pre, WoutT, b_out, out, nq, ED);
    }
}

// Round 10
// 265.102 us; speedup vs baseline: 1.2769x; 1.0540x over previous
//
#include <hip/hip_runtime.h>
#include <math.h>

#define ED      256       // EMBED_DIM
#define NL      4
#define NH      8
#define NP      4
#define HD      32        // HEAD_DIM
#define HMAX    128
#define WMAX    128
#define NLP     16        // NL*NP
#define NC      128       // NL*NP*NH
#define NOFF_AW 384       // 256 off cols + 128 attn cols
#define QPB     4         // queries per block in sampler
#define NBK     1024      // sort buckets
#define BSTRIDE (HMAX*WMAX*NL*ED)   // 16,777,216 elements
#define XSTRIDE (WMAX*NL*ED)        // 131,072
#define YSTRIDE (NL*ED)             // 1,024
#define RPB     21760               // compact rows per batch: 128^2+64^2+32^2+16^2
#define PBC     (RPB*256)           // compact elems per batch

typedef __attribute__((ext_vector_type(8))) __fp16   f16x8;
typedef __attribute__((ext_vector_type(4))) __fp16   f16x4;
typedef __attribute__((ext_vector_type(4))) float    f32x4;

__constant__ int LBASE_ROW[4] = {0, 16384, 20480, 21504};

// ---------------- Kprep: V compaction into HEAD-MAJOR f16 layout ----------
// Vc[b][level l][head h][x*sz + y][32 dims] -- 64-B rows; (x,y) and (x,y+1)
// are contiguous 128 B so a bilinear y-pair is one segment.
//                + weight transpose/convert + query locality sort ----------
__global__ __launch_bounds__(1024) void msda_prep_kernel(
    const float* __restrict__ V,
    const float* __restrict__ W_off,
    const float* __restrict__ W_attn,
    const float* __restrict__ W_out,
    const float* __restrict__ refp,
    const int*   __restrict__ batch_off,
    int n_batch,
    __fp16* __restrict__ Vc,
    __fp16* __restrict__ WcatT,
    __fp16* __restrict__ WoutT,
    int* __restrict__ bucket_of,
    int* __restrict__ perm,
    int nq, int nb, int nCompact, int nWconv)
{
    __shared__ int cnt[NBK];
    __shared__ int scan[NBK];
    const int bid = blockIdx.x;
    const int t   = threadIdx.x;

    if (bid < nCompact) {
        const int r    = bid * 16 + (t >> 6);
        const int lane = t & 63;
        const int h    = lane >> 3;
        const int j4   = lane & 7;
        const int total_rows = nb * RPB;
        if (r < total_rows) {
            const int b  = r / RPB;
            const int rr = r - b * RPB;
            int l, base;
            if (rr < 16384)      { l = 0; base = 0; }
            else if (rr < 20480) { l = 1; base = 16384; }
            else if (rr < 21504) { l = 2; base = 20480; }
            else                 { l = 3; base = 21504; }
            const int pos = rr - base;            // x*sz + y within level
            const int lsh = 7 - l;
            const int xi  = pos >> lsh;
            const int yi  = pos & ((1 << lsh) - 1);
            const int plane32 = (1 << (2 * lsh)) * 32;   // per-head plane elems
            const float4 src = *(const float4*)&V[(size_t)b * BSTRIDE +
                (size_t)xi * XSTRIDE + (size_t)yi * YSTRIDE + l * ED +
                h * HD + j4 * 4];
            f16x4 d;
            d[0] = (__fp16)src.x; d[1] = (__fp16)src.y;
            d[2] = (__fp16)src.z; d[3] = (__fp16)src.w;
            const size_t dst = (size_t)b * PBC + (size_t)LBASE_ROW[l] * 256 +
                               (size_t)h * plane32 + (size_t)pos * 32 + j4 * 4;
            *(f16x4*)&Vc[dst] = d;
        }
    } else if (bid < nCompact + nWconv) {
        const int idx = (bid - nCompact) * 1024 + t;
        const int t2 = NOFF_AW * ED;
        const int t3 = ED * ED;
        if (idx < t2) {
            int c = idx >> 8, e = idx & 255;
            float v = (c < ED) ? W_off[e * ED + c] : W_attn[e * NC + (c - ED)];
            WcatT[idx] = (__fp16)v;
        } else if (idx < t2 + t3) {
            int i = idx - t2;
            int c = i >> 8, e = i & 255;
            WoutT[i] = (__fp16)W_out[e * ED + c];
        }
    } else {
        // ---- locality sort: bucket by (batch, 16x16 ref tile) ----
        cnt[t] = 0;
        __syncthreads();
        const int iters = (nq + 1023) >> 10;
        for (int i = 0; i < iters; ++i) {
            int q = i * 1024 + t;
            if (q < nq) {
                int b = 0;
                for (int j = 1; j < n_batch; ++j)
                    if (batch_off[j] <= q) b = j;
                b = min(b, 3);
                float rx = refp[q * 2 + 0], ry = refp[q * 2 + 1];
                int bx = min(15, max(0, (int)(rx * 16.f)));
                int by = min(15, max(0, (int)(ry * 16.f)));
                int bk = (b << 8) | (by << 4) | bx;
                bucket_of[q] = bk;
                atomicAdd(&cnt[bk], 1);
            }
        }
        __syncthreads();
        scan[t] = cnt[t];
        __syncthreads();
        for (int d = 1; d < NBK; d <<= 1) {
            int v = scan[t];
            int u = (t >= d) ? scan[t - d] : 0;
            __syncthreads();
            scan[t] = v + u;
            __syncthreads();
        }
        cnt[t] = scan[t] - cnt[t];
        __syncthreads();
        for (int i = 0; i < iters; ++i) {
            int q = i * 1024 + t;
            if (q < nq) {
                int bk = bucket_of[q];
                int pos = atomicAdd(&cnt[bk], 1);
                perm[pos] = q;
            }
        }
    }
}

// ------- K1: f16 2-pass MFMA GEMM: C = (Ah+Al) @ Bh^T + bias --------------
__global__ __launch_bounds__(256) void gemm_f16_kernel(
    const float*  __restrict__ A,     // (M,256) f32
    const __fp16* __restrict__ BT,    // (NTOT,256) f16
    const float* __restrict__ bias0,
    const float* __restrict__ bias1,
    float* __restrict__ C,
    int M, int NTOT, int bias_split)
{
    const int wave = threadIdx.x >> 6;
    const int lane = threadIdx.x & 63;
    const int gw   = blockIdx.x * 4 + wave;
    const int ngroups = NTOT >> 6;
    const int mg = gw / ngroups, ng = gw % ngroups;
    const int m16 = mg * 16, n64 = ng * 64;
    if (m16 >= M) return;

    const int mrow = lane & 15;
    const int quad = lane >> 4;

    const float4* Arow = (const float4*)(A + (size_t)(m16 + mrow) * 256 + quad * 8);
    const f16x8* B0 = (const f16x8*)(BT + (size_t)(n64 +  0 + mrow) * 256 + quad * 8);
    const f16x8* B1 = (const f16x8*)(BT + (size_t)(n64 + 16 + mrow) * 256 + quad * 8);
    const f16x8* B2 = (const f16x8*)(BT + (size_t)(n64 + 32 + mrow) * 256 + quad * 8);
    const f16x8* B3 = (const f16x8*)(BT + (size_t)(n64 + 48 + mrow) * 256 + quad * 8);

    f32x4 acc0 = {0.f,0.f,0.f,0.f}, acc1 = acc0, acc2 = acc0, acc3 = acc0;
    #pragma unroll
    for (int kb = 0; kb < 8; ++kb) {
        float4 a0 = Arow[kb * 8 + 0];
        float4 a1 = Arow[kb * 8 + 1];
        float av[8] = {a0.x, a0.y, a0.z, a0.w, a1.x, a1.y, a1.z, a1.w};
        f16x8 ah, al;
        #pragma unroll
        for (int j = 0; j < 8; ++j) {
            __fp16 h = (__fp16)av[j];
            ah[j] = h;
            al[j] = (__fp16)(av[j] - (float)h);
        }
        f16x8 b0 = B0[kb * 4], b1 = B1[kb * 4], b2 = B2[kb * 4], b3 = B3[kb * 4];
        acc0 = __builtin_amdgcn_mfma_f32_16x16x32_f16(ah, b0, acc0, 0, 0, 0);
        acc1 = __builtin_amdgcn_mfma_f32_16x16x32_f16(ah, b1, acc1, 0, 0, 0);
        acc2 = __builtin_amdgcn_mfma_f32_16x16x32_f16(ah, b2, acc2, 0, 0, 0);
        acc3 = __builtin_amdgcn_mfma_f32_16x16x32_f16(ah, b3, acc3, 0, 0, 0);
        acc0 = __builtin_amdgcn_mfma_f32_16x16x32_f16(al, b0, acc0, 0, 0, 0);
        acc1 = __builtin_amdgcn_mfma_f32_16x16x32_f16(al, b1, acc1, 0, 0, 0);
        acc2 = __builtin_amdgcn_mfma_f32_16x16x32_f16(al, b2, acc2, 0, 0, 0);
        acc3 = __builtin_amdgcn_mfma_f32_16x16x32_f16(al, b3, acc3, 0, 0, 0);
    }

    const int col = lane & 15;
    f32x4 accs[4] = {acc0, acc1, acc2, acc3};
    #pragma unroll
    for (int i = 0; i < 4; ++i) {
        int n = n64 + i * 16 + col;
        float b = (n < bias_split) ? bias0[n] : bias1[n - bias_split];
        #pragma unroll
        for (int r = 0; r < 4; ++r) {
            int row = m16 + quad * 4 + r;
            C[(size_t)row * NTOT + n] = accs[i][r] + b;
        }
    }
}

// ---------------- K3: plain f16 MFMA GEMM ---------------------------------
__global__ __launch_bounds__(256) void gemm_ff16_kernel(
    const __fp16* __restrict__ A,     // (M,256) f16
    const __fp16* __restrict__ BT,    // (NTOT,256) f16
    const float* __restrict__ bias,
    float* __restrict__ C,
    int M, int NTOT)
{
    const int wave = threadIdx.x >> 6;
    const int lane = threadIdx.x & 63;
    const int gw   = blockIdx.x * 4 + wave;
    const int ngroups = NTOT >> 6;
    const int mg = gw / ngroups, ng = gw % ngroups;
    const int m16 = mg * 16, n64 = ng * 64;
    if (m16 >= M) return;

    const int mrow = lane & 15;
    const int quad = lane >> 4;

    const f16x8* Arow = (const f16x8*)(A + (size_t)(m16 + mrow) * 256 + quad * 8);
    const f16x8* B0 = (const f16x8*)(BT + (size_t)(n64 +  0 + mrow) * 256 + quad * 8);
    const f16x8* B1 = (const f16x8*)(BT + (size_t)(n64 + 16 + mrow) * 256 + quad * 8);
    const f16x8* B2 = (const f16x8*)(BT + (size_t)(n64 + 32 + mrow) * 256 + quad * 8);
    const f16x8* B3 = (const f16x8*)(BT + (size_t)(n64 + 48 + mrow) * 256 + quad * 8);

    f32x4 acc0 = {0.f,0.f,0.f,0.f}, acc1 = acc0, acc2 = acc0, acc3 = acc0;
    #pragma unroll
    for (int kb = 0; kb < 8; ++kb) {
        f16x8 af = Arow[kb * 4];
        acc0 = __builtin_amdgcn_mfma_f32_16x16x32_f16(af, B0[kb * 4], acc0, 0, 0, 0);
        acc1 = __builtin_amdgcn_mfma_f32_16x16x32_f16(af, B1[kb * 4], acc1, 0, 0, 0);
        acc2 = __builtin_amdgcn_mfma_f32_16x16x32_f16(af, B2[kb * 4], acc2, 0, 0, 0);
        acc3 = __builtin_amdgcn_mfma_f32_16x16x32_f16(af, B3[kb * 4], acc3, 0, 0, 0);
    }

    const int col = lane & 15;
    f32x4 accs[4] = {acc0, acc1, acc2, acc3};
    #pragma unroll
    for (int i = 0; i < 4; ++i) {
        int n = n64 + i * 16 + col;
        float b = bias[n];
        #pragma unroll
        for (int r = 0; r < 4; ++r) {
            int row = m16 + quad * 4 + r;
            C[(size_t)row * NTOT + n] = accs[i][r] + b;
        }
    }
}

// ---------------- K2: softmax + sampling + PAIRED bilinear gather ---------
// Head-major Vc: y-pair (y0,y0+1) contiguous 128 B; one f16x8 load per
// 8-lane head group covers both y-corners -> 2 loads/sample vs 4.
// y-clip handled by weight folding (w01/w11 -> 0).
__global__ __launch_bounds__(256) void msda_sample_kernel(
    const float*  __restrict__ refp,     // (Q, 2)
    const __fp16* __restrict__ Vc,       // compact head-major f16 V
    const float*  __restrict__ off_aw,   // (Q, 384)
    const int*    __restrict__ perm,     // (Q) locality-sorted ids
    const int*    __restrict__ batch_off,
    int n_batch,
    __fp16* __restrict__ out_pre,        // (Q, 256) f16
    int q_total)
{
    __shared__ int    sqid[QPB];
    __shared__ float  law[QPB][NC];
    __shared__ float2 sminv[QPB][NH];
    __shared__ float2 sref[QPB];
    __shared__ int2   soff[QPB][NC];     // pairA (x0), pairB (x1) elem offsets
    __shared__ float4 swt[QPB][NC];      // folded w00,w01,w10,w11

    const int t = threadIdx.x;
    const int chunk = gridDim.x >> 3;
    const int pblk  = (blockIdx.x & 7) * chunk + (blockIdx.x >> 3);
    const int q0 = pblk * QPB;

    if (t < QPB) sqid[t] = perm[q0 + t];
    __syncthreads();

    // ---- load attn logits ----
    {
        const int s = t >> 6, c = t & 63;
        const float* row = off_aw + (size_t)sqid[s] * NOFF_AW + ED;
        law[s][c]      = row[c];
        law[s][c + 64] = row[c + 64];
    }
    __syncthreads();

    // ---- softmax stats + ref-point prep ----
    if (t < QPB * NH) {
        const int s = t >> 3, h = t & 7;
        float m = -1e30f;
        #pragma unroll
        for (int lp = 0; lp < NLP; ++lp) m = fmaxf(m, law[s][lp * NH + h]);
        float sum = 0.f;
        #pragma unroll
        for (int lp = 0; lp < NLP; ++lp) sum += __expf(law[s][lp * NH + h] - m);
        sminv[s][h] = make_float2(m, 1.f / sum);
    } else if (t < QPB * NH + QPB) {
        const int s = t - QPB * NH;
        const int qid = sqid[s];
        float rx = refp[qid * 2 + 0], ry = refp[qid * 2 + 1];
        rx = fminf(fmaxf(rx, 0.f), 1.f);
        ry = fminf(fmaxf(ry, 0.f), 1.f);
        float ivx = __logf(fmaxf(rx, 1e-5f) / fmaxf(1.f - rx, 1e-5f));
        float ivy = __logf(fmaxf(ry, 1e-5f) / fmaxf(1.f - ry, 1e-5f));
        sref[s] = make_float2(ivx, ivy);
    }
    __syncthreads();

    // ---- sampling params: pair offsets + folded weights ----
    {
        const int s = t >> 6;
        const int qid = sqid[s];
        int b = 0;
        for (int i = 1; i < n_batch; ++i)
            if (batch_off[i] <= qid) b = i;
        const int cb = b * PBC;
        const float2 iv = sref[s];
        const float* offrow = off_aw + (size_t)qid * NOFF_AW;

        #pragma unroll
        for (int half = 0; half < 2; ++half) {
            const int c = (t & 63) + half * 64;
            const int l = c >> 5;
            const int lsh = 7 - l;
            const int sz  = 1 << lsh;
            const int cap = sz - 1;
            const int h = c & 7;
            const int plane32 = (sz * sz) << 5;

            const float2 mi = sminv[s][h];
            const float a = __expf(law[s][c] - mi.x) * mi.y;

            const float ox = offrow[c * 2 + 0], oy = offrow[c * 2 + 1];
            float lx = 2.f / (1.f + __expf(-(iv.x + ox))) - 1.f;
            float ly = 2.f / (1.f + __expf(-(iv.y + oy))) - 1.f;
            float x = ((lx + 1.f) * (float)sz - 1.f) * 0.5f;
            float y = ((ly + 1.f) * (float)sz - 1.f) * 0.5f;
            int x0 = (int)floorf(x), y0 = (int)floorf(y);
            int x1 = x0 + 1, y1 = y0 + 1;
            x0 = min(max(x0, 0), cap); x1 = min(max(x1, 0), cap);
            y0 = min(max(y0, 0), cap); y1 = min(max(y1, 0), cap);
            float x0f = (float)x0, x1f = (float)x1;
            float y0f = (float)y0, y1f = (float)y1;

            float w00 = a * (x1f - x) * (y1f - y);
            float w01 = a * (x1f - x) * (y - y0f);
            float w10 = a * (x - x0f) * (y1f - y);
            float w11 = a * (x - x0f) * (y - y0f);
            if (y1 == y0) {        // y-clip: both corners same row; row y0+1
                w00 += w01; w01 = 0.f;   // in the pair gets weight 0
                w10 += w11; w11 = 0.f;
            }
            swt[s][c] = make_float4(w00, w01, w10, w11);
            const int lb = cb + (LBASE_ROW[l] << 8) + h * plane32;
            int2 o;
            o.x = lb + (((x0 << lsh) + y0) << 5);
            o.y = lb + (((x1 << lsh) + y0) << 5);
            soff[s][c] = o;
        }
    }
    __syncthreads();

    // ---- gather: one wave per query; lane = (h, j); paired f16x8 loads ---
    {
        const int s    = t >> 6;
        const int lane = t & 63;
        const int h    = lane >> 3;
        const int j    = lane & 7;
        const int top  = j >> 2;        // 0: row y0, 1: row y1
        const int blk  = j & 3;         // dim block [8*blk .. 8*blk+7]

        float acc[8];
        #pragma unroll
        for (int k = 0; k < 8; ++k) acc[k] = 0.f;

        #pragma unroll 4
        for (int lp = 0; lp < NLP; ++lp) {
            const int c = lp * NH + h;
            int2   o = soff[s][c];
            float4 w = swt[s][c];
            f16x8 va = *(const f16x8*)&Vc[o.x + j * 8];   // x0 pair
            f16x8 vb = *(const f16x8*)&Vc[o.y + j * 8];   // x1 pair
            const float wa = top ? w.y : w.x;
            const float wb = top ? w.w : w.z;
            #pragma unroll
            for (int k = 0; k < 8; ++k)
                acc[k] += wa * (float)va[k] + wb * (float)vb[k];
        }
        // lanes j and j^4 hold the same dim block for rows y0/y1 -> combine
        #pragma unroll
        for (int k = 0; k < 8; ++k)
            acc[k] += __shfl_xor(acc[k], 4);

        if (top == 0) {
            f16x8 o8;
            #pragma unroll
            for (int k = 0; k < 8; ++k) o8[k] = (__fp16)acc[k];
            *(f16x8*)&out_pre[(size_t)sqid[s] * ED + h * HD + blk * 8] = o8;
        }
    }
}

extern "C" void kernel_launch(void* const* d_in, const int* in_sizes, int n_in,
                              void* d_out, int out_size, void* d_ws, size_t ws_size,
                              hipStream_t stream) {
    const float* query  = (const float*)d_in[0];
    const float* refp   = (const float*)d_in[1];
    const float* V      = (const float*)d_in[2];
    const float* W_off  = (const float*)d_in[3];
    const float* b_off  = (const float*)d_in[4];
    const float* W_attn = (const float*)d_in[5];
    const float* b_attn = (const float*)d_in[6];
    const float* W_out  = (const float*)d_in[7];
    const float* b_out  = (const float*)d_in[8];
    const int*   boff   = (const int*)d_in[9];
    const int n_batch   = in_sizes[9];
    const int nq        = in_sizes[0] / ED;
    const int nb        = in_sizes[2] / BSTRIDE;
    float* out = (float*)d_out;

    // workspace layout (all chunks 16B-aligned); Vc padded 256 elems for the
    // (x=cap,y=cap) pair read that bleeds 64 B past the last row.
    char* ws = (char*)d_ws;
    float*   off_aw    = (float*)ws;                             // nq*384 f32
    int*     perm      = (int*)(off_aw + (size_t)nq * NOFF_AW);  // nq int
    int*     bucket_of = perm + nq;                              // nq int
    __fp16*  WcatT     = (__fp16*)(bucket_of + nq);              // 384*256 f16
    __fp16*  WoutT     = WcatT + NOFF_AW * ED;                   // 256*256 f16
    __fp16*  out_pre   = WoutT + ED * ED;                        // nq*256 f16
    __fp16*  Vc        = out_pre + (size_t)nq * ED;              // nb*RPB*256+pad

    // Kprep: V compaction (head-major) + weight conversion + locality sort
    {
        int nCompact = (nb * RPB + 15) / 16;
        int nWconv   = (NOFF_AW * ED + ED * ED + 1023) / 1024;
        msda_prep_kernel<<<nCompact + nWconv + 1, 1024, 0, stream>>>(
            V, W_off, W_attn, W_out, refp, boff, n_batch,
            Vc, WcatT, WoutT, bucket_of, perm, nq, nb, nCompact, nWconv);
    }
    // K1: [off|aw] = q @ [W_off|W_attn] + bias  (f16 2-pass, A exact)
    {
        int waves = (nq / 16) * (NOFF_AW / 64);
        gemm_f16_kernel<<<(waves + 3) / 4, 256, 0, stream>>>(
            query, WcatT, b_off, b_attn, off_aw, nq, NOFF_AW, ED);
    }
    // K2: sampling + paired gather -> out_pre
    {
        msda_sample_kernel<<<nq / QPB, 256, 0, stream>>>(
            refp, Vc, off_aw, perm, boff, n_batch, out_pre, nq);
    }
    // K3: out = out_pre @ W_out + b_out
    {
        int waves = (nq / 16) * (ED / 64);
        gemm_ff16_kernel<<<(waves + 3) / 4, 256, 0, stream>>>(
            out_pre, WoutT, b_out, out, nq, ED);
    }
}

// Round 11
// 255.936 us; speedup vs baseline: 1.3226x; 1.0358x over previous
//
#include <hip/hip_runtime.h>
#include <math.h>

#define ED      256       // EMBED_DIM
#define NL      4
#define NH      8
#define NP      4
#define HD      32        // HEAD_DIM
#define HMAX    128
#define WMAX    128
#define NLP     16        // NL*NP
#define NC      128       // NL*NP*NH
#define NOFF_AW 384       // 256 off cols + 128 attn cols
#define QPB     4         // queries per block in sampler
#define BSTRIDE (HMAX*WMAX*NL*ED)   // 16,777,216 elements
#define XSTRIDE (WMAX*NL*ED)        // 131,072
#define YSTRIDE (NL*ED)             // 1,024
#define RPB     21760               // compact rows per batch: 128^2+64^2+32^2+16^2
#define PBC     (RPB*256)           // compact elems per batch

typedef __attribute__((ext_vector_type(8))) __fp16   f16x8;
typedef __attribute__((ext_vector_type(4))) __fp16   f16x4;
typedef __attribute__((ext_vector_type(4))) float    f32x4;

__constant__ int LBASE_ROW[4] = {0, 16384, 20480, 21504};

// ---------------- Kprep: V compaction into HEAD-MAJOR f16 layout ----------
// Vc[b][level l][head h][x*sz + y][32 dims] -- 64-B rows; (x,y) and (x,y+1)
// contiguous 128 B so a bilinear y-pair is one segment.
// + weight transpose/convert. (Locality sort removed: measured benefit ~0,
// and its single-block scan was Kprep's critical-path straggler.)
__global__ __launch_bounds__(1024) void msda_prep_kernel(
    const float* __restrict__ V,
    const float* __restrict__ W_off,
    const float* __restrict__ W_attn,
    const float* __restrict__ W_out,
    __fp16* __restrict__ Vc,
    __fp16* __restrict__ WcatT,
    __fp16* __restrict__ WoutT,
    int nb, int nCompact)
{
    const int bid = blockIdx.x;
    const int t   = threadIdx.x;

    if (bid < nCompact) {
        const int r    = bid * 16 + (t >> 6);
        const int lane = t & 63;
        const int h    = lane >> 3;
        const int j4   = lane & 7;
        const int total_rows = nb * RPB;
        if (r < total_rows) {
            const int b  = r / RPB;
            const int rr = r - b * RPB;
            int l;
            if (rr < 16384)      { l = 0; }
            else if (rr < 20480) { l = 1; }
            else if (rr < 21504) { l = 2; }
            else                 { l = 3; }
            const int pos = rr - LBASE_ROW[l];    // x*sz + y within level
            const int lsh = 7 - l;
            const int xi  = pos >> lsh;
            const int yi  = pos & ((1 << lsh) - 1);
            const int plane32 = (1 << (2 * lsh)) * 32;   // per-head plane elems
            const float4 src = *(const float4*)&V[(size_t)b * BSTRIDE +
                (size_t)xi * XSTRIDE + (size_t)yi * YSTRIDE + l * ED +
                h * HD + j4 * 4];
            f16x4 d;
            d[0] = (__fp16)src.x; d[1] = (__fp16)src.y;
            d[2] = (__fp16)src.z; d[3] = (__fp16)src.w;
            const size_t dst = (size_t)b * PBC + (size_t)LBASE_ROW[l] * 256 +
                               (size_t)h * plane32 + (size_t)pos * 32 + j4 * 4;
            *(f16x4*)&Vc[dst] = d;
        }
    } else {
        const int idx = (bid - nCompact) * 1024 + t;
        const int t2 = NOFF_AW * ED;
        const int t3 = ED * ED;
        if (idx < t2) {
            int c = idx >> 8, e = idx & 255;
            float v = (c < ED) ? W_off[e * ED + c] : W_attn[e * NC + (c - ED)];
            WcatT[idx] = (__fp16)v;
        } else if (idx < t2 + t3) {
            int i = idx - t2;
            int c = i >> 8, e = i & 255;
            WoutT[i] = (__fp16)W_out[e * ED + c];
        }
    }
}

// ------- K1: f16 2-pass MFMA GEMM: C = (Ah+Al) @ Bh^T + bias --------------
__global__ __launch_bounds__(256) void gemm_f16_kernel(
    const float*  __restrict__ A,     // (M,256) f32
    const __fp16* __restrict__ BT,    // (NTOT,256) f16
    const float* __restrict__ bias0,
    const float* __restrict__ bias1,
    float* __restrict__ C,
    int M, int NTOT, int bias_split)
{
    const int wave = threadIdx.x >> 6;
    const int lane = threadIdx.x & 63;
    const int gw   = blockIdx.x * 4 + wave;
    const int ngroups = NTOT >> 6;
    const int mg = gw / ngroups, ng = gw % ngroups;
    const int m16 = mg * 16, n64 = ng * 64;
    if (m16 >= M) return;

    const int mrow = lane & 15;
    const int quad = lane >> 4;

    const float4* Arow = (const float4*)(A + (size_t)(m16 + mrow) * 256 + quad * 8);
    const f16x8* B0 = (const f16x8*)(BT + (size_t)(n64 +  0 + mrow) * 256 + quad * 8);
    const f16x8* B1 = (const f16x8*)(BT + (size_t)(n64 + 16 + mrow) * 256 + quad * 8);
    const f16x8* B2 = (const f16x8*)(BT + (size_t)(n64 + 32 + mrow) * 256 + quad * 8);
    const f16x8* B3 = (const f16x8*)(BT + (size_t)(n64 + 48 + mrow) * 256 + quad * 8);

    f32x4 acc0 = {0.f,0.f,0.f,0.f}, acc1 = acc0, acc2 = acc0, acc3 = acc0;
    #pragma unroll
    for (int kb = 0; kb < 8; ++kb) {
        float4 a0 = Arow[kb * 8 + 0];
        float4 a1 = Arow[kb * 8 + 1];
        float av[8] = {a0.x, a0.y, a0.z, a0.w, a1.x, a1.y, a1.z, a1.w};
        f16x8 ah, al;
        #pragma unroll
        for (int j = 0; j < 8; ++j) {
            __fp16 h = (__fp16)av[j];
            ah[j] = h;
            al[j] = (__fp16)(av[j] - (float)h);
        }
        f16x8 b0 = B0[kb * 4], b1 = B1[kb * 4], b2 = B2[kb * 4], b3 = B3[kb * 4];
        acc0 = __builtin_amdgcn_mfma_f32_16x16x32_f16(ah, b0, acc0, 0, 0, 0);
        acc1 = __builtin_amdgcn_mfma_f32_16x16x32_f16(ah, b1, acc1, 0, 0, 0);
        acc2 = __builtin_amdgcn_mfma_f32_16x16x32_f16(ah, b2, acc2, 0, 0, 0);
        acc3 = __builtin_amdgcn_mfma_f32_16x16x32_f16(ah, b3, acc3, 0, 0, 0);
        acc0 = __builtin_amdgcn_mfma_f32_16x16x32_f16(al, b0, acc0, 0, 0, 0);
        acc1 = __builtin_amdgcn_mfma_f32_16x16x32_f16(al, b1, acc1, 0, 0, 0);
        acc2 = __builtin_amdgcn_mfma_f32_16x16x32_f16(al, b2, acc2, 0, 0, 0);
        acc3 = __builtin_amdgcn_mfma_f32_16x16x32_f16(al, b3, acc3, 0, 0, 0);
    }

    const int col = lane & 15;
    f32x4 accs[4] = {acc0, acc1, acc2, acc3};
    #pragma unroll
    for (int i = 0; i < 4; ++i) {
        int n = n64 + i * 16 + col;
        float b = (n < bias_split) ? bias0[n] : bias1[n - bias_split];
        #pragma unroll
        for (int r = 0; r < 4; ++r) {
            int row = m16 + quad * 4 + r;
            C[(size_t)row * NTOT + n] = accs[i][r] + b;
        }
    }
}

// ---------------- K3: plain f16 MFMA GEMM ---------------------------------
__global__ __launch_bounds__(256) void gemm_ff16_kernel(
    const __fp16* __restrict__ A,     // (M,256) f16
    const __fp16* __restrict__ BT,    // (NTOT,256) f16
    const float* __restrict__ bias,
    float* __restrict__ C,
    int M, int NTOT)
{
    const int wave = threadIdx.x >> 6;
    const int lane = threadIdx.x & 63;
    const int gw   = blockIdx.x * 4 + wave;
    const int ngroups = NTOT >> 6;
    const int mg = gw / ngroups, ng = gw % ngroups;
    const int m16 = mg * 16, n64 = ng * 64;
    if (m16 >= M) return;

    const int mrow = lane & 15;
    const int quad = lane >> 4;

    const f16x8* Arow = (const f16x8*)(A + (size_t)(m16 + mrow) * 256 + quad * 8);
    const f16x8* B0 = (const f16x8*)(BT + (size_t)(n64 +  0 + mrow) * 256 + quad * 8);
    const f16x8* B1 = (const f16x8*)(BT + (size_t)(n64 + 16 + mrow) * 256 + quad * 8);
    const f16x8* B2 = (const f16x8*)(BT + (size_t)(n64 + 32 + mrow) * 256 + quad * 8);
    const f16x8* B3 = (const f16x8*)(BT + (size_t)(n64 + 48 + mrow) * 256 + quad * 8);

    f32x4 acc0 = {0.f,0.f,0.f,0.f}, acc1 = acc0, acc2 = acc0, acc3 = acc0;
    #pragma unroll
    for (int kb = 0; kb < 8; ++kb) {
        f16x8 af = Arow[kb * 4];
        acc0 = __builtin_amdgcn_mfma_f32_16x16x32_f16(af, B0[kb * 4], acc0, 0, 0, 0);
        acc1 = __builtin_amdgcn_mfma_f32_16x16x32_f16(af, B1[kb * 4], acc1, 0, 0, 0);
        acc2 = __builtin_amdgcn_mfma_f32_16x16x32_f16(af, B2[kb * 4], acc2, 0, 0, 0);
        acc3 = __builtin_amdgcn_mfma_f32_16x16x32_f16(af, B3[kb * 4], acc3, 0, 0, 0);
    }

    const int col = lane & 15;
    f32x4 accs[4] = {acc0, acc1, acc2, acc3};
    #pragma unroll
    for (int i = 0; i < 4; ++i) {
        int n = n64 + i * 16 + col;
        float b = bias[n];
        #pragma unroll
        for (int r = 0; r < 4; ++r) {
            int row = m16 + quad * 4 + r;
            C[(size_t)row * NTOT + n] = accs[i][r] + b;
        }
    }
}

// ---------------- K2: softmax + sampling + PAIRED bilinear gather ---------
__global__ __launch_bounds__(256) void msda_sample_kernel(
    const float*  __restrict__ refp,     // (Q, 2)
    const __fp16* __restrict__ Vc,       // compact head-major f16 V
    const float*  __restrict__ off_aw,   // (Q, 384)
    const int*    __restrict__ batch_off,
    int n_batch,
    __fp16* __restrict__ out_pre,        // (Q, 256) f16
    int q_total)
{
    __shared__ float  law[QPB][NC];
    __shared__ float2 sminv[QPB][NH];
    __shared__ float2 sref[QPB];
    __shared__ int2   soff[QPB][NC];     // pairA (x0), pairB (x1) elem offsets
    __shared__ float4 swt[QPB][NC];      // folded w00,w01,w10,w11

    const int t  = threadIdx.x;
    const int q0 = blockIdx.x * QPB;

    // ---- load attn logits ----
    {
        const int s = t >> 6, c = t & 63;
        const float* row = off_aw + (size_t)(q0 + s) * NOFF_AW + ED;
        law[s][c]      = row[c];
        law[s][c + 64] = row[c + 64];
    }
    __syncthreads();

    // ---- softmax stats + ref-point prep ----
    if (t < QPB * NH) {
        const int s = t >> 3, h = t & 7;
        float m = -1e30f;
        #pragma unroll
        for (int lp = 0; lp < NLP; ++lp) m = fmaxf(m, law[s][lp * NH + h]);
        float sum = 0.f;
        #pragma unroll
        for (int lp = 0; lp < NLP; ++lp) sum += __expf(law[s][lp * NH + h] - m);
        sminv[s][h] = make_float2(m, 1.f / sum);
    } else if (t < QPB * NH + QPB) {
        const int s = t - QPB * NH;
        const int qid = q0 + s;
        float rx = refp[qid * 2 + 0], ry = refp[qid * 2 + 1];
        rx = fminf(fmaxf(rx, 0.f), 1.f);
        ry = fminf(fmaxf(ry, 0.f), 1.f);
        float ivx = __logf(fmaxf(rx, 1e-5f) / fmaxf(1.f - rx, 1e-5f));
        float ivy = __logf(fmaxf(ry, 1e-5f) / fmaxf(1.f - ry, 1e-5f));
        sref[s] = make_float2(ivx, ivy);
    }
    __syncthreads();

    // ---- sampling params: pair offsets + folded weights ----
    {
        const int s = t >> 6;
        const int qid = q0 + s;
        int b = 0;
        for (int i = 1; i < n_batch; ++i)
            if (batch_off[i] <= qid) b = i;
        const int cb = b * PBC;
        const float2 iv = sref[s];
        const float* offrow = off_aw + (size_t)qid * NOFF_AW;

        #pragma unroll
        for (int half = 0; half < 2; ++half) {
            const int c = (t & 63) + half * 64;
            const int l = c >> 5;
            const int lsh = 7 - l;
            const int sz  = 1 << lsh;
            const int cap = sz - 1;
            const int h = c & 7;
            const int plane32 = (sz * sz) << 5;

            const float2 mi = sminv[s][h];
            const float a = __expf(law[s][c] - mi.x) * mi.y;

            const float ox = offrow[c * 2 + 0], oy = offrow[c * 2 + 1];
            float lx = 2.f / (1.f + __expf(-(iv.x + ox))) - 1.f;
            float ly = 2.f / (1.f + __expf(-(iv.y + oy))) - 1.f;
            float x = ((lx + 1.f) * (float)sz - 1.f) * 0.5f;
            float y = ((ly + 1.f) * (float)sz - 1.f) * 0.5f;
            int x0 = (int)floorf(x), y0 = (int)floorf(y);
            int x1 = x0 + 1, y1 = y0 + 1;
            x0 = min(max(x0, 0), cap); x1 = min(max(x1, 0), cap);
            y0 = min(max(y0, 0), cap); y1 = min(max(y1, 0), cap);
            float x0f = (float)x0, x1f = (float)x1;
            float y0f = (float)y0, y1f = (float)y1;

            float w00 = a * (x1f - x) * (y1f - y);
            float w01 = a * (x1f - x) * (y - y0f);
            float w10 = a * (x - x0f) * (y1f - y);
            float w11 = a * (x - x0f) * (y - y0f);
            if (y1 == y0) {        // y-clip: fold weight; padded row gets 0
                w00 += w01; w01 = 0.f;
                w10 += w11; w11 = 0.f;
            }
            swt[s][c] = make_float4(w00, w01, w10, w11);
            const int lb = cb + (LBASE_ROW[l] << 8) + h * plane32;
            int2 o;
            o.x = lb + (((x0 << lsh) + y0) << 5);
            o.y = lb + (((x1 << lsh) + y0) << 5);
            soff[s][c] = o;
        }
    }
    __syncthreads();

    // ---- gather: one wave per query; lane = (h, j); paired f16x8 loads ---
    {
        const int s    = t >> 6;
        const int lane = t & 63;
        const int h    = lane >> 3;
        const int j    = lane & 7;
        const int top  = j >> 2;        // 0: row y0, 1: row y1
        const int blk  = j & 3;         // dim block [8*blk .. 8*blk+7]

        float acc[8];
        #pragma unroll
        for (int k = 0; k < 8; ++k) acc[k] = 0.f;

        #pragma unroll 4
        for (int lp = 0; lp < NLP; ++lp) {
            const int c = lp * NH + h;
            int2   o = soff[s][c];
            float4 w = swt[s][c];
            f16x8 va = *(const f16x8*)&Vc[o.x + j * 8];   // x0 pair
            f16x8 vb = *(const f16x8*)&Vc[o.y + j * 8];   // x1 pair
            const float wa = top ? w.y : w.x;
            const float wb = top ? w.w : w.z;
            #pragma unroll
            for (int k = 0; k < 8; ++k)
                acc[k] += wa * (float)va[k] + wb * (float)vb[k];
        }
        // lanes j and j^4 hold the same dim block for rows y0/y1 -> combine
        #pragma unroll
        for (int k = 0; k < 8; ++k)
            acc[k] += __shfl_xor(acc[k], 4);

        if (top == 0) {
            f16x8 o8;
            #pragma unroll
            for (int k = 0; k < 8; ++k) o8[k] = (__fp16)acc[k];
            *(f16x8*)&out_pre[(size_t)(q0 + s) * ED + h * HD + blk * 8] = o8;
        }
    }
}

extern "C" void kernel_launch(void* const* d_in, const int* in_sizes, int n_in,
                              void* d_out, int out_size, void* d_ws, size_t ws_size,
                              hipStream_t stream) {
    const float* query  = (const float*)d_in[0];
    const float* refp   = (const float*)d_in[1];
    const float* V      = (const float*)d_in[2];
    const float* W_off  = (const float*)d_in[3];
    const float* b_off  = (const float*)d_in[4];
    const float* W_attn = (const float*)d_in[5];
    const float* b_attn = (const float*)d_in[6];
    const float* W_out  = (const float*)d_in[7];
    const float* b_out  = (const float*)d_in[8];
    const int*   boff   = (const int*)d_in[9];
    const int n_batch   = in_sizes[9];
    const int nq        = in_sizes[0] / ED;
    const int nb        = in_sizes[2] / BSTRIDE;
    float* out = (float*)d_out;

    // workspace layout (16B-aligned chunks); Vc tail pad covers the
    // (x=cap,y=cap) pair read that bleeds 64 B past the last row.
    char* ws = (char*)d_ws;
    float*   off_aw  = (float*)ws;                              // nq*384 f32
    __fp16*  WcatT   = (__fp16*)(off_aw + (size_t)nq * NOFF_AW);// 384*256 f16
    __fp16*  WoutT   = WcatT + NOFF_AW * ED;                    // 256*256 f16
    __fp16*  out_pre = WoutT + ED * ED;                         // nq*256 f16
    __fp16*  Vc      = out_pre + (size_t)nq * ED;               // nb*RPB*256+pad

    // Kprep: V compaction (head-major) + weight conversion
    {
        int nCompact = (nb * RPB + 15) / 16;
        int nWconv   = (NOFF_AW * ED + ED * ED + 1023) / 1024;
        msda_prep_kernel<<<nCompact + nWconv, 1024, 0, stream>>>(
            V, W_off, W_attn, W_out, Vc, WcatT, WoutT, nb, nCompact);
    }
    // K1: [off|aw] = q @ [W_off|W_attn] + bias  (f16 2-pass, A exact)
    {
        int waves = (nq / 16) * (NOFF_AW / 64);
        gemm_f16_kernel<<<(waves + 3) / 4, 256, 0, stream>>>(
            query, WcatT, b_off, b_attn, off_aw, nq, NOFF_AW, ED);
    }
    // K2: sampling + paired gather -> out_pre
    {
        msda_sample_kernel<<<nq / QPB, 256, 0, stream>>>(
            refp, Vc, off_aw, boff, n_batch, out_pre, nq);
    }
    // K3: out = out_pre @ W_out + b_out
    {
        int waves = (nq / 16) * (ED / 64);
        gemm_ff16_kernel<<<(waves + 3) / 4, 256, 0, stream>>>(
            out_pre, WoutT, b_out, out, nq, ED);
    }
}